// Round 13
// baseline (345.059 us; speedup 1.0000x reference)
//
#include <hip/hip_runtime.h>
#include <hip/hip_bf16.h>

// GraphSAGE forward (R13 = R12 + column-group-split h/agg layout for L2-resident gathers):
//   h and agg stored as hg[4][n][16] bf16 (4 col-groups). agg blocks pick group = bid&3 so each
//   XCD (bid%8 round-robin) only touches one 3.2MB slice -> gathers hit per-XCD L2.
//   Structure: bin1 -> bin2 (inline base scan) -> wconv -> lin1 (MFMA) ->
//   3x [agg + MFMA GEMM(norm,relu)]; layer-3 GEMM also applies W2 -> f32 out.

#define NT 256
#define BATCH 4096        // edges per bin1 block (NT * 16)
#define SBCAP 8192        // slots per super-bucket region (mean 6378 for m=1.25M)
#define HSTRIDE 72        // h3 LDS tile row stride (bf16)

typedef __attribute__((ext_vector_type(8))) short bf16x8;
typedef __attribute__((ext_vector_type(4))) float f32x4;

__device__ __forceinline__ float bfbits2f(unsigned short b) {
    return __uint_as_float(((unsigned)b) << 16);
}
__device__ __forceinline__ unsigned short f2bfbits(float v) {
    __hip_bfloat16 b = __float2bfloat16(v);
    return *reinterpret_cast<unsigned short*>(&b);
}

// ---------------- CSR build: two-level binning ----------------

__global__ __launch_bounds__(NT) void bin1_kernel(const int* __restrict__ src,
    const int* __restrict__ dst, int m, unsigned* __restrict__ gcur,
    unsigned* __restrict__ bins) {
    __shared__ unsigned hist[256];
    __shared__ unsigned gbase[256];
    const int t = threadIdx.x;
    const int base = blockIdx.x * BATCH;
    hist[t] = 0;
    __syncthreads();
    int d[16], s[16];
    const int e0 = base + t * 16;
    const bool full = (base + BATCH) <= m;
    if (full) {
        #pragma unroll
        for (int q = 0; q < 4; ++q) {
            const int4 dv = *(const int4*)&dst[e0 + q * 4];
            const int4 sv = *(const int4*)&src[e0 + q * 4];
            d[q*4+0]=dv.x; d[q*4+1]=dv.y; d[q*4+2]=dv.z; d[q*4+3]=dv.w;
            s[q*4+0]=sv.x; s[q*4+1]=sv.y; s[q*4+2]=sv.z; s[q*4+3]=sv.w;
        }
        #pragma unroll
        for (int q = 0; q < 16; ++q) atomicAdd(&hist[d[q] >> 9], 1u);
    } else {
        #pragma unroll
        for (int q = 0; q < 16; ++q) {
            const int e = e0 + q;
            if (e < m) { d[q] = dst[e]; s[q] = src[e]; atomicAdd(&hist[d[q] >> 9], 1u); }
            else d[q] = -1;
        }
    }
    __syncthreads();
    {
        const unsigned h = hist[t];
        gbase[t] = h ? atomicAdd(&gcur[t], h) : 0u;
        hist[t] = 0;                       // reuse as per-bucket cursor
    }
    __syncthreads();
    if (full) {
        #pragma unroll
        for (int q = 0; q < 16; ++q) {
            const int b = d[q] >> 9;
            const unsigned slot = gbase[b] + atomicAdd(&hist[b], 1u);
            bins[(size_t)b * SBCAP + slot] = ((unsigned)s[q] << 9) | (unsigned)(d[q] & 511);
        }
    } else {
        #pragma unroll
        for (int q = 0; q < 16; ++q) {
            if (d[q] >= 0) {
                const int b = d[q] >> 9;
                const unsigned slot = gbase[b] + atomicAdd(&hist[b], 1u);
                bins[(size_t)b * SBCAP + slot] = ((unsigned)s[q] << 9) | (unsigned)(d[q] & 511);
            }
        }
    }
}

// bin2: per super-bucket; computes its own base by scanning gcur (<=256 words) in-block.
__global__ __launch_bounds__(NT) void bin2_kernel(const unsigned* __restrict__ bins,
    const unsigned* __restrict__ gcur, int* __restrict__ row_ptr, int* __restrict__ csr,
    int n, int nsb, int m) {
    __shared__ unsigned hist[512];
    __shared__ unsigned off[512];
    __shared__ unsigned cur[512];
    __shared__ unsigned wsum[4];
    __shared__ unsigned gpre[256];
    const int k = blockIdx.x;
    const int t = threadIdx.x;
    const int lane = t & 63, wid = t >> 6;

    {
        const unsigned gv = (t < nsb) ? gcur[t] : 0u;
        unsigned gx = gv;
        #pragma unroll
        for (int o = 1; o < 64; o <<= 1) {
            const unsigned tt = __shfl_up(gx, o, 64);
            if (lane >= o) gx += tt;
        }
        if (lane == 63) wsum[wid] = gx;
        __syncthreads();
        unsigned wo = 0;
        for (int w = 0; w < wid; ++w) wo += wsum[w];
        gpre[t] = wo + gx - gv;
        __syncthreads();
    }
    const int cnt = (int)gcur[k];
    const unsigned sb = gpre[k];
    if (k == 0 && t == 0) row_ptr[n] = m;

    const unsigned* reg = bins + (size_t)k * SBCAP;
    hist[2*t] = 0; hist[2*t+1] = 0;
    __syncthreads();
    for (int i = t; i < cnt; i += NT) atomicAdd(&hist[reg[i] & 511u], 1u);
    __syncthreads();
    const unsigned v0 = hist[2*t], v1 = hist[2*t+1];
    const unsigned ps = v0 + v1;
    unsigned x = ps;
    #pragma unroll
    for (int o = 1; o < 64; o <<= 1) {
        const unsigned tt = __shfl_up(x, o, 64);
        if (lane >= o) x += tt;
    }
    if (lane == 63) wsum[wid] = x;
    __syncthreads();
    unsigned woff = 0;
    for (int w = 0; w < wid; ++w) woff += wsum[w];
    const unsigned excl = woff + x - ps;
    off[2*t] = excl; off[2*t+1] = excl + v0;
    cur[2*t] = 0; cur[2*t+1] = 0;
    const int node = k * 512 + 2 * t;
    if (node < n)     row_ptr[node]     = (int)(sb + excl);
    if (node + 1 < n) row_ptr[node + 1] = (int)(sb + excl + v0);
    __syncthreads();
    for (int i = t; i < cnt; i += NT) {
        const unsigned u = reg[i];
        const unsigned l = u & 511u;
        const unsigned r = atomicAdd(&cur[l], 1u);
        csr[sb + off[l] + r] = (int)(u >> 9);
    }
}

// ---------------- weight convert+transpose: Wt[col][k] bf16 ----------------

__global__ void wconv_kernel(const float* __restrict__ W1, const float* __restrict__ Wl,
                             const float* __restrict__ Wr, const float* __restrict__ W2,
                             unsigned short* __restrict__ out) {
    int i = blockIdx.x * blockDim.x + threadIdx.x;
    if (i >= 36864) return;
    float v;
    if (i < 8192) {
        const int col = i >> 7, k = i & 127;
        v = W1[k * 64 + col];
    } else if (i < 32768) {
        const int j = i - 8192;
        const int mm = j >> 13, r = j & 8191;
        const int isR = (r >> 12) & 1, q = r & 4095;
        const int col = q >> 6, k = q & 63;
        v = (isR ? Wr : Wl)[mm * 4096 + k * 64 + col];
    } else {
        const int q = i - 32768;
        const int col = q >> 6, k = q & 63;
        v = W2[k * 64 + col];
    }
    out[i] = f2bfbits(v);
}

// ---------------- aggregation, column-group-split ----------------
// h layout: hg[grp][node][16] bf16 (grp = col>>4). Block's group = bid&3 -> per-XCD L2 slice.
// Wave: 8 edge slots (gs=lane>>3) x 8 col-lanes (c=lane&7, ushort2 = 2 cols).

__global__ __launch_bounds__(NT) void agg_kernel(const unsigned short* __restrict__ h,
    const int* __restrict__ row_ptr, const int* __restrict__ csr,
    unsigned short* __restrict__ aggB, int n) {
    const int t = threadIdx.x;
    const int lane = t & 63;
    const int gs = lane >> 3;
    const int c = lane & 7;
    const int grp = blockIdx.x & 3;
    const int gw = ((blockIdx.x >> 2) * NT + t) >> 6;
    const int nw = ((gridDim.x >> 2) * NT) >> 6;
    const unsigned short* hg = h + (size_t)grp * n * 16;
    unsigned short* ag = aggB + (size_t)grp * n * 16;
    for (int node = gw; node < n; node += nw) {
        const int rs = row_ptr[node];
        const int re = row_ptr[node + 1];
        float a0 = 0.f, a1 = 0.f;
        int e = rs;
        for (; e + 16 <= re; e += 16) {
            const int s0 = csr[e + gs];
            const int s1 = csr[e + 8 + gs];
            const ushort2 v0 = *(const ushort2*)&hg[(size_t)s0 * 16 + c * 2];
            const ushort2 v1 = *(const ushort2*)&hg[(size_t)s1 * 16 + c * 2];
            a0 += bfbits2f(v0.x) + bfbits2f(v1.x);
            a1 += bfbits2f(v0.y) + bfbits2f(v1.y);
        }
        for (; e + 8 <= re; e += 8) {
            const int s0 = csr[e + gs];
            const ushort2 v0 = *(const ushort2*)&hg[(size_t)s0 * 16 + c * 2];
            a0 += bfbits2f(v0.x);
            a1 += bfbits2f(v0.y);
        }
        const int r = re - e;
        if (gs < r) {
            const int s0 = csr[e + gs];
            const ushort2 v0 = *(const ushort2*)&hg[(size_t)s0 * 16 + c * 2];
            a0 += bfbits2f(v0.x);
            a1 += bfbits2f(v0.y);
        }
        // reduce across the 8 edge slots (lane bits 3,4,5)
        a0 += __shfl_xor(a0, 8, 64);  a1 += __shfl_xor(a1, 8, 64);
        a0 += __shfl_xor(a0, 16, 64); a1 += __shfl_xor(a1, 16, 64);
        a0 += __shfl_xor(a0, 32, 64); a1 += __shfl_xor(a1, 32, 64);
        if (gs == 0) {
            const float inv = (re > rs) ? (1.0f / (float)(re - rs)) : 0.0f;
            ushort2 o;
            o.x = f2bfbits(a0 * inv);
            o.y = f2bfbits(a1 * inv);
            *(ushort2*)&ag[(size_t)node * 16 + c * 2] = o;
        }
    }
}

// ---------------- MFMA GEMM ----------------
// A1F32: A1 = f32 row-major (lin1).  else: A1b/A2b in hg[4][n][16] layout.
// outB writes hg layout; LAST also runs out = h3@W2t2 + b2 (f32 row-major).
// C/D: col = lane&15, row = (lane>>4)*4 + reg.

template<int A1F32, int LAST>
__global__ __launch_bounds__(NT) void gemm_mfma(
    const float* __restrict__ A1f, const unsigned short* __restrict__ A1b,
    int ldA1, int K1, const unsigned short* __restrict__ W1t,
    const unsigned short* __restrict__ A2b, const unsigned short* __restrict__ W2t,
    const float* __restrict__ bias, float* __restrict__ outF,
    unsigned short* __restrict__ outB, int n, int do_norm,
    const unsigned short* __restrict__ W2t2, const float* __restrict__ b2) {
    const int t = threadIdx.x;
    const int lane = t & 63;
    const int w = t >> 6;
    const int r16 = lane & 15;
    const int g = lane >> 4;
    const int row0 = blockIdx.x * 128 + w * 32;

    f32x4 acc[2][4];
    #pragma unroll
    for (int i = 0; i < 2; ++i)
        #pragma unroll
        for (int j = 0; j < 4; ++j) {
            acc[i][j][0] = 0.f; acc[i][j][1] = 0.f; acc[i][j][2] = 0.f; acc[i][j][3] = 0.f;
        }

    int ra[2];
    #pragma unroll
    for (int rt = 0; rt < 2; ++rt) {
        int r = row0 + rt * 16 + r16;
        ra[rt] = (r < n) ? r : (n - 1);
    }

    #pragma unroll 1
    for (int kc = 0; kc < K1; kc += 32) {
        bf16x8 af[2];
        #pragma unroll
        for (int rt = 0; rt < 2; ++rt) {
            if (A1F32) {
                const float* p = &A1f[(size_t)ra[rt] * ldA1 + kc + g * 8];
                const float4 f0 = *(const float4*)p;
                const float4 f1 = *(const float4*)(p + 4);
                bf16x8 a;
                a[0] = (short)f2bfbits(f0.x); a[1] = (short)f2bfbits(f0.y);
                a[2] = (short)f2bfbits(f0.z); a[3] = (short)f2bfbits(f0.w);
                a[4] = (short)f2bfbits(f1.x); a[5] = (short)f2bfbits(f1.y);
                a[6] = (short)f2bfbits(f1.z); a[7] = (short)f2bfbits(f1.w);
                af[rt] = a;
            } else {
                const int grp = (kc >> 4) + (g >> 1);
                const int lo = (g & 1) * 8;
                af[rt] = *(const bf16x8*)&A1b[((size_t)grp * n + ra[rt]) * 16 + lo];
            }
        }
        #pragma unroll
        for (int ct = 0; ct < 4; ++ct) {
            const bf16x8 bw = *(const bf16x8*)&W1t[(size_t)(ct * 16 + r16) * K1 + kc + g * 8];
            acc[0][ct] = __builtin_amdgcn_mfma_f32_16x16x32_bf16(af[0], bw, acc[0][ct], 0, 0, 0);
            acc[1][ct] = __builtin_amdgcn_mfma_f32_16x16x32_bf16(af[1], bw, acc[1][ct], 0, 0, 0);
        }
    }
    if (A2b) {
        #pragma unroll 1
        for (int kc = 0; kc < 64; kc += 32) {
            bf16x8 af[2];
            #pragma unroll
            for (int rt = 0; rt < 2; ++rt) {
                const int grp = (kc >> 4) + (g >> 1);
                const int lo = (g & 1) * 8;
                af[rt] = *(const bf16x8*)&A2b[((size_t)grp * n + ra[rt]) * 16 + lo];
            }
            #pragma unroll
            for (int ct = 0; ct < 4; ++ct) {
                const bf16x8 bw = *(const bf16x8*)&W2t[(size_t)(ct * 16 + r16) * 64 + kc + g * 8];
                acc[0][ct] = __builtin_amdgcn_mfma_f32_16x16x32_bf16(af[0], bw, acc[0][ct], 0, 0, 0);
                acc[1][ct] = __builtin_amdgcn_mfma_f32_16x16x32_bf16(af[1], bw, acc[1][ct], 0, 0, 0);
            }
        }
    }

    float bcol[4];
    #pragma unroll
    for (int ct = 0; ct < 4; ++ct) bcol[ct] = bias[ct * 16 + r16];

    #pragma unroll
    for (int rt = 0; rt < 2; ++rt) {
        #pragma unroll
        for (int ct = 0; ct < 4; ++ct)
            #pragma unroll
            for (int reg = 0; reg < 4; ++reg) acc[rt][ct][reg] += bcol[ct];

        if (do_norm) {
            #pragma unroll
            for (int reg = 0; reg < 4; ++reg) {
                float ss = 0.f;
                #pragma unroll
                for (int ct = 0; ct < 4; ++ct) ss += acc[rt][ct][reg] * acc[rt][ct][reg];
                ss += __shfl_xor(ss, 1, 64);
                ss += __shfl_xor(ss, 2, 64);
                ss += __shfl_xor(ss, 4, 64);
                ss += __shfl_xor(ss, 8, 64);
                const float inv = 1.0f / fmaxf(sqrtf(ss), 1e-12f);
                #pragma unroll
                for (int ct = 0; ct < 4; ++ct)
                    acc[rt][ct][reg] = fmaxf(acc[rt][ct][reg] * inv, 0.0f);
            }
        }
    }

    if constexpr (!LAST) {
        // write hg layout: col = ct*16 + r16 -> grp = ct, lo = r16
        #pragma unroll
        for (int rt = 0; rt < 2; ++rt) {
            const int rbase = row0 + rt * 16 + g * 4;
            #pragma unroll
            for (int reg = 0; reg < 4; ++reg) {
                const int rr = rbase + reg;
                if (rr < n) {
                    #pragma unroll
                    for (int ct = 0; ct < 4; ++ct)
                        outB[((size_t)ct * n + rr) * 16 + r16] = f2bfbits(acc[rt][ct][reg]);
                }
            }
        }
    } else {
        // stage h3 tile in LDS, then out = h3 @ W2t2 + b2 (f32 row-major)
        __shared__ unsigned short h3S[128][HSTRIDE];   // 18 KB
        #pragma unroll
        for (int rt = 0; rt < 2; ++rt) {
            #pragma unroll
            for (int reg = 0; reg < 4; ++reg) {
                const int lr = w * 32 + rt * 16 + g * 4 + reg;
                #pragma unroll
                for (int ct = 0; ct < 4; ++ct)
                    h3S[lr][ct * 16 + r16] = f2bfbits(acc[rt][ct][reg]);
            }
        }
        __syncthreads();
        f32x4 acc2[2][4];
        #pragma unroll
        for (int i = 0; i < 2; ++i)
            #pragma unroll
            for (int j = 0; j < 4; ++j) { acc2[i][j][0]=0.f; acc2[i][j][1]=0.f; acc2[i][j][2]=0.f; acc2[i][j][3]=0.f; }
        #pragma unroll
        for (int kc = 0; kc < 64; kc += 32) {
            bf16x8 af[2];
            #pragma unroll
            for (int rt = 0; rt < 2; ++rt)
                af[rt] = *(const bf16x8*)&h3S[w * 32 + rt * 16 + r16][kc + g * 8];
            #pragma unroll
            for (int ct = 0; ct < 4; ++ct) {
                const bf16x8 bw = *(const bf16x8*)&W2t2[(size_t)(ct * 16 + r16) * 64 + kc + g * 8];
                acc2[0][ct] = __builtin_amdgcn_mfma_f32_16x16x32_bf16(af[0], bw, acc2[0][ct], 0, 0, 0);
                acc2[1][ct] = __builtin_amdgcn_mfma_f32_16x16x32_bf16(af[1], bw, acc2[1][ct], 0, 0, 0);
            }
        }
        float b2c[4];
        #pragma unroll
        for (int ct = 0; ct < 4; ++ct) b2c[ct] = b2[ct * 16 + r16];
        #pragma unroll
        for (int rt = 0; rt < 2; ++rt) {
            const int rbase = row0 + rt * 16 + g * 4;
            #pragma unroll
            for (int reg = 0; reg < 4; ++reg) {
                const int rr = rbase + reg;
                if (rr < n) {
                    #pragma unroll
                    for (int ct = 0; ct < 4; ++ct)
                        outF[(size_t)rr * 64 + ct * 16 + r16] = acc2[rt][ct][reg] + b2c[ct];
                }
            }
        }
    }
}

// ---------------- launch ----------------

extern "C" void kernel_launch(void* const* d_in, const int* in_sizes, int n_in,
                              void* d_out, int out_size, void* d_ws, size_t ws_size,
                              hipStream_t stream) {
    const float* x  = (const float*)d_in[0];
    const int*   ei = (const int*)  d_in[1];
    const float* W1 = (const float*)d_in[2];
    const float* b1 = (const float*)d_in[3];
    const float* Wl = (const float*)d_in[4];
    const float* bl = (const float*)d_in[5];
    const float* Wr = (const float*)d_in[6];
    const float* W2 = (const float*)d_in[7];
    const float* b2 = (const float*)d_in[8];
    float* out = (float*)d_out;

    const int n = in_sizes[0] / 128;   // 100000
    const int m = in_sizes[1] / 2;     // 1250000
    const int* src = ei;
    const int* dst = ei + m;

    const int nsb = (n + 511) >> 9;    // 196 super-buckets (<= 256)

    char* ws = (char*)d_ws;
    size_t off = 0;
    auto alloc = [&](size_t bytes) -> void* {
        void* p = ws + off;
        off = (off + bytes + 255) & ~(size_t)255;
        return p;
    };
    unsigned short* aggB    = (unsigned short*)alloc((size_t)n * 64 * 2);
    unsigned short* hbf     = (unsigned short*)alloc((size_t)n * 64 * 2);
    int*            row_ptr = (int*)alloc((size_t)(n + 1) * sizeof(int));
    unsigned*       gcur    = (unsigned*)alloc((size_t)nsb * 4);
    unsigned*       bins    = (unsigned*)alloc((size_t)nsb * SBCAP * 4);
    int*            csr     = (int*)alloc((size_t)m * 4);
    unsigned short* wt      = (unsigned short*)alloc(36864 * 2);

    const unsigned short* W1t = wt;
    const unsigned short* W2t = wt + 32768;

    hipMemsetAsync(gcur, 0, (size_t)nsb * 4, stream);

    const int nb1 = (m + BATCH - 1) / BATCH;   // 306
    const int gtiles = (n + 127) / 128;        // 782

    wconv_kernel<<<144, NT, 0, stream>>>(W1, Wl, Wr, W2, wt);

    // h0 = x @ W1 + b1 -> hbf (hg layout)
    gemm_mfma<1, 0><<<gtiles, NT, 0, stream>>>(x, nullptr, 128, 128, W1t,
                                               nullptr, nullptr, b1, nullptr, hbf, n, 0,
                                               nullptr, nullptr);

    // two-level binned CSR build
    bin1_kernel<<<nb1, NT, 0, stream>>>(src, dst, m, gcur, bins);
    bin2_kernel<<<nsb, NT, 0, stream>>>(bins, gcur, row_ptr, csr, n, nsb, m);

    // layers 1,2: agg + GEMM(norm,relu), h in-place; layer 3: GEMM also applies W2 -> out
    for (int i = 0; i < 2; ++i) {
        agg_kernel<<<2048, NT, 0, stream>>>(hbf, row_ptr, csr, aggB, n);
        const unsigned short* Wlt = wt + 8192 + (size_t)i * 8192;
        const unsigned short* Wrt = Wlt + 4096;
        gemm_mfma<0, 0><<<gtiles, NT, 0, stream>>>(nullptr, aggB, 64, 64, Wlt,
                                                   hbf, Wrt, bl + (size_t)i * 64,
                                                   nullptr, hbf, n, 1, nullptr, nullptr);
    }
    agg_kernel<<<2048, NT, 0, stream>>>(hbf, row_ptr, csr, aggB, n);
    gemm_mfma<0, 1><<<gtiles, NT, 0, stream>>>(nullptr, aggB, 64, 64, wt + 8192 + 16384,
                                               hbf, wt + 8192 + 16384 + 4096, bl + 128,
                                               out, nullptr, n, 1, W2t, b2);
}

// Round 14
// 204.433 us; speedup vs baseline: 1.6879x; 1.6879x over previous
//
#include <hip/hip_runtime.h>
#include <hip/hip_bf16.h>

// GraphSAGE forward (R14 = R12 + 2-nodes-per-wave agg + gcur-zero folded into wconv):
//   bin1 -> bin2 (inline base scan) -> wconv(+gcur zero) -> lin1 (MFMA) ->
//   3x [agg (half-wave = one node; 2 slots x 16 col-lanes) + MFMA GEMM(norm,relu)];
//   layer-3 GEMM also applies W2 -> f32 out. h row-major bf16 [n][64].

#define NT 256
#define BATCH 4096        // edges per bin1 block (NT * 16)
#define SBCAP 8192        // slots per super-bucket region (mean 6378 for m=1.25M)
#define HSTRIDE 72        // h3 LDS tile row stride (bf16)

typedef __attribute__((ext_vector_type(8))) short bf16x8;
typedef __attribute__((ext_vector_type(4))) float f32x4;

__device__ __forceinline__ float bfbits2f(unsigned short b) {
    return __uint_as_float(((unsigned)b) << 16);
}
__device__ __forceinline__ unsigned short f2bfbits(float v) {
    __hip_bfloat16 b = __float2bfloat16(v);
    return *reinterpret_cast<unsigned short*>(&b);
}

// ---------------- CSR build: two-level binning ----------------

__global__ __launch_bounds__(NT) void bin1_kernel(const int* __restrict__ src,
    const int* __restrict__ dst, int m, unsigned* __restrict__ gcur,
    unsigned* __restrict__ bins) {
    __shared__ unsigned hist[256];
    __shared__ unsigned gbase[256];
    const int t = threadIdx.x;
    const int base = blockIdx.x * BATCH;
    hist[t] = 0;
    __syncthreads();
    int d[16], s[16];
    const int e0 = base + t * 16;
    const bool full = (base + BATCH) <= m;
    if (full) {
        #pragma unroll
        for (int q = 0; q < 4; ++q) {
            const int4 dv = *(const int4*)&dst[e0 + q * 4];
            const int4 sv = *(const int4*)&src[e0 + q * 4];
            d[q*4+0]=dv.x; d[q*4+1]=dv.y; d[q*4+2]=dv.z; d[q*4+3]=dv.w;
            s[q*4+0]=sv.x; s[q*4+1]=sv.y; s[q*4+2]=sv.z; s[q*4+3]=sv.w;
        }
        #pragma unroll
        for (int q = 0; q < 16; ++q) atomicAdd(&hist[d[q] >> 9], 1u);
    } else {
        #pragma unroll
        for (int q = 0; q < 16; ++q) {
            const int e = e0 + q;
            if (e < m) { d[q] = dst[e]; s[q] = src[e]; atomicAdd(&hist[d[q] >> 9], 1u); }
            else d[q] = -1;
        }
    }
    __syncthreads();
    {
        const unsigned h = hist[t];
        gbase[t] = h ? atomicAdd(&gcur[t], h) : 0u;
        hist[t] = 0;                       // reuse as per-bucket cursor
    }
    __syncthreads();
    if (full) {
        #pragma unroll
        for (int q = 0; q < 16; ++q) {
            const int b = d[q] >> 9;
            const unsigned slot = gbase[b] + atomicAdd(&hist[b], 1u);
            bins[(size_t)b * SBCAP + slot] = ((unsigned)s[q] << 9) | (unsigned)(d[q] & 511);
        }
    } else {
        #pragma unroll
        for (int q = 0; q < 16; ++q) {
            if (d[q] >= 0) {
                const int b = d[q] >> 9;
                const unsigned slot = gbase[b] + atomicAdd(&hist[b], 1u);
                bins[(size_t)b * SBCAP + slot] = ((unsigned)s[q] << 9) | (unsigned)(d[q] & 511);
            }
        }
    }
}

// bin2: per super-bucket; computes its own base by scanning gcur (<=256 words) in-block.
__global__ __launch_bounds__(NT) void bin2_kernel(const unsigned* __restrict__ bins,
    const unsigned* __restrict__ gcur, int* __restrict__ row_ptr, int* __restrict__ csr,
    int n, int nsb, int m) {
    __shared__ unsigned hist[512];
    __shared__ unsigned off[512];
    __shared__ unsigned cur[512];
    __shared__ unsigned wsum[4];
    __shared__ unsigned gpre[256];
    const int k = blockIdx.x;
    const int t = threadIdx.x;
    const int lane = t & 63, wid = t >> 6;

    {
        const unsigned gv = (t < nsb) ? gcur[t] : 0u;
        unsigned gx = gv;
        #pragma unroll
        for (int o = 1; o < 64; o <<= 1) {
            const unsigned tt = __shfl_up(gx, o, 64);
            if (lane >= o) gx += tt;
        }
        if (lane == 63) wsum[wid] = gx;
        __syncthreads();
        unsigned wo = 0;
        for (int w = 0; w < wid; ++w) wo += wsum[w];
        gpre[t] = wo + gx - gv;
        __syncthreads();
    }
    const int cnt = (int)gcur[k];
    const unsigned sb = gpre[k];
    if (k == 0 && t == 0) row_ptr[n] = m;

    const unsigned* reg = bins + (size_t)k * SBCAP;
    hist[2*t] = 0; hist[2*t+1] = 0;
    __syncthreads();
    for (int i = t; i < cnt; i += NT) atomicAdd(&hist[reg[i] & 511u], 1u);
    __syncthreads();
    const unsigned v0 = hist[2*t], v1 = hist[2*t+1];
    const unsigned ps = v0 + v1;
    unsigned x = ps;
    #pragma unroll
    for (int o = 1; o < 64; o <<= 1) {
        const unsigned tt = __shfl_up(x, o, 64);
        if (lane >= o) x += tt;
    }
    if (lane == 63) wsum[wid] = x;
    __syncthreads();
    unsigned woff = 0;
    for (int w = 0; w < wid; ++w) woff += wsum[w];
    const unsigned excl = woff + x - ps;
    off[2*t] = excl; off[2*t+1] = excl + v0;
    cur[2*t] = 0; cur[2*t+1] = 0;
    const int node = k * 512 + 2 * t;
    if (node < n)     row_ptr[node]     = (int)(sb + excl);
    if (node + 1 < n) row_ptr[node + 1] = (int)(sb + excl + v0);
    __syncthreads();
    for (int i = t; i < cnt; i += NT) {
        const unsigned u = reg[i];
        const unsigned l = u & 511u;
        const unsigned r = atomicAdd(&cur[l], 1u);
        csr[sb + off[l] + r] = (int)(u >> 9);
    }
}

// ---------------- weight convert+transpose (+ gcur zeroing): Wt[col][k] bf16 ----------------

__global__ void wconv_kernel(const float* __restrict__ W1, const float* __restrict__ Wl,
                             const float* __restrict__ Wr, const float* __restrict__ W2,
                             unsigned short* __restrict__ out, unsigned* __restrict__ gcur,
                             int nsb) {
    int i = blockIdx.x * blockDim.x + threadIdx.x;
    if (i < nsb) gcur[i] = 0u;
    if (i >= 36864) return;
    float v;
    if (i < 8192) {
        const int col = i >> 7, k = i & 127;
        v = W1[k * 64 + col];
    } else if (i < 32768) {
        const int j = i - 8192;
        const int mm = j >> 13, r = j & 8191;
        const int isR = (r >> 12) & 1, q = r & 4095;
        const int col = q >> 6, k = q & 63;
        v = (isR ? Wr : Wl)[mm * 4096 + k * 64 + col];
    } else {
        const int q = i - 32768;
        const int col = q >> 6, k = q & 63;
        v = W2[k * 64 + col];
    }
    out[i] = f2bfbits(v);
}

// ---------------- aggregation: 2 nodes per wave (half-wave each) ----------------
// half = lane>>5 -> node 2p+half; within half: gs = (lane>>4)&1 (2 edge slots),
// c = lane&15 (4 cols each, ushort4). One gather instr = 4 edges x 128 B, two
// independent node chains in flight; reduce = 1 shfl_xor round.

__global__ __launch_bounds__(NT) void agg_kernel(const unsigned short* __restrict__ h,
    const int* __restrict__ row_ptr, const int* __restrict__ csr,
    unsigned short* __restrict__ aggB, int n) {
    const int t = threadIdx.x;
    const int lane = t & 63;
    const int half = lane >> 5;
    const int gs = (lane >> 4) & 1;
    const int c = lane & 15;
    const int gw = (blockIdx.x * NT + t) >> 6;
    const int nw = (gridDim.x * NT) >> 6;
    const int npairs = (n + 1) >> 1;
    for (int p = gw; p < npairs; p += nw) {
        const int node = p * 2 + half;
        const bool valid = node < n;
        const int node_c = valid ? node : (n - 1);
        const int rs = row_ptr[node_c];
        const int re = row_ptr[node_c + 1];
        float a0 = 0.f, a1 = 0.f, a2 = 0.f, a3 = 0.f;
        int e = rs;
        for (; e + 8 <= re; e += 8) {
            const int s0 = csr[e + gs];
            const int s1 = csr[e + 2 + gs];
            const int s2 = csr[e + 4 + gs];
            const int s3 = csr[e + 6 + gs];
            const ushort4 v0 = *(const ushort4*)&h[(size_t)s0 * 64 + c * 4];
            const ushort4 v1 = *(const ushort4*)&h[(size_t)s1 * 64 + c * 4];
            const ushort4 v2 = *(const ushort4*)&h[(size_t)s2 * 64 + c * 4];
            const ushort4 v3 = *(const ushort4*)&h[(size_t)s3 * 64 + c * 4];
            a0 += (bfbits2f(v0.x) + bfbits2f(v1.x)) + (bfbits2f(v2.x) + bfbits2f(v3.x));
            a1 += (bfbits2f(v0.y) + bfbits2f(v1.y)) + (bfbits2f(v2.y) + bfbits2f(v3.y));
            a2 += (bfbits2f(v0.z) + bfbits2f(v1.z)) + (bfbits2f(v2.z) + bfbits2f(v3.z));
            a3 += (bfbits2f(v0.w) + bfbits2f(v1.w)) + (bfbits2f(v2.w) + bfbits2f(v3.w));
        }
        for (; e + 4 <= re; e += 4) {
            const int s0 = csr[e + gs];
            const int s1 = csr[e + 2 + gs];
            const ushort4 v0 = *(const ushort4*)&h[(size_t)s0 * 64 + c * 4];
            const ushort4 v1 = *(const ushort4*)&h[(size_t)s1 * 64 + c * 4];
            a0 += bfbits2f(v0.x) + bfbits2f(v1.x);
            a1 += bfbits2f(v0.y) + bfbits2f(v1.y);
            a2 += bfbits2f(v0.z) + bfbits2f(v1.z);
            a3 += bfbits2f(v0.w) + bfbits2f(v1.w);
        }
        for (; e + 2 <= re; e += 2) {
            const int s0 = csr[e + gs];
            const ushort4 v0 = *(const ushort4*)&h[(size_t)s0 * 64 + c * 4];
            a0 += bfbits2f(v0.x);
            a1 += bfbits2f(v0.y);
            a2 += bfbits2f(v0.z);
            a3 += bfbits2f(v0.w);
        }
        if (gs < re - e) {
            const int s0 = csr[e + gs];
            const ushort4 v0 = *(const ushort4*)&h[(size_t)s0 * 64 + c * 4];
            a0 += bfbits2f(v0.x);
            a1 += bfbits2f(v0.y);
            a2 += bfbits2f(v0.z);
            a3 += bfbits2f(v0.w);
        }
        // reduce across the 2 edge slots (lane bit 4; stays within each half)
        a0 += __shfl_xor(a0, 16, 64);
        a1 += __shfl_xor(a1, 16, 64);
        a2 += __shfl_xor(a2, 16, 64);
        a3 += __shfl_xor(a3, 16, 64);
        if (gs == 0 && valid) {
            const float inv = (re > rs) ? (1.0f / (float)(re - rs)) : 0.0f;
            ushort4 o;
            o.x = f2bfbits(a0 * inv);
            o.y = f2bfbits(a1 * inv);
            o.z = f2bfbits(a2 * inv);
            o.w = f2bfbits(a3 * inv);
            *(ushort4*)&aggB[(size_t)node * 64 + c * 4] = o;
        }
    }
}

// ---------------- MFMA GEMM: C = A1@W1 [+ A2@W2] + bias; optional norm; LAST: + (C@W2t2 + b2) ----------------
// block = 4 waves, wave = 32 rows x 64 cols (2 row-tiles x 4 col-tiles of 16x16x32 mfma).
// C/D: col = lane&15, row = (lane>>4)*4 + reg.

template<int A1F32, int LAST>
__global__ __launch_bounds__(NT) void gemm_mfma(
    const float* __restrict__ A1f, const unsigned short* __restrict__ A1b,
    int ldA1, int K1, const unsigned short* __restrict__ W1t,
    const unsigned short* __restrict__ A2b, const unsigned short* __restrict__ W2t,
    const float* __restrict__ bias, float* __restrict__ outF,
    unsigned short* __restrict__ outB, int n, int do_norm,
    const unsigned short* __restrict__ W2t2, const float* __restrict__ b2) {
    const int t = threadIdx.x;
    const int lane = t & 63;
    const int w = t >> 6;
    const int r16 = lane & 15;
    const int g = lane >> 4;
    const int row0 = blockIdx.x * 128 + w * 32;

    f32x4 acc[2][4];
    #pragma unroll
    for (int i = 0; i < 2; ++i)
        #pragma unroll
        for (int j = 0; j < 4; ++j) {
            acc[i][j][0] = 0.f; acc[i][j][1] = 0.f; acc[i][j][2] = 0.f; acc[i][j][3] = 0.f;
        }

    int ra[2];
    #pragma unroll
    for (int rt = 0; rt < 2; ++rt) {
        int r = row0 + rt * 16 + r16;
        ra[rt] = (r < n) ? r : (n - 1);
    }

    #pragma unroll 1
    for (int kc = 0; kc < K1; kc += 32) {
        bf16x8 af[2];
        #pragma unroll
        for (int rt = 0; rt < 2; ++rt) {
            if (A1F32) {
                const float* p = &A1f[(size_t)ra[rt] * ldA1 + kc + g * 8];
                const float4 f0 = *(const float4*)p;
                const float4 f1 = *(const float4*)(p + 4);
                bf16x8 a;
                a[0] = (short)f2bfbits(f0.x); a[1] = (short)f2bfbits(f0.y);
                a[2] = (short)f2bfbits(f0.z); a[3] = (short)f2bfbits(f0.w);
                a[4] = (short)f2bfbits(f1.x); a[5] = (short)f2bfbits(f1.y);
                a[6] = (short)f2bfbits(f1.z); a[7] = (short)f2bfbits(f1.w);
                af[rt] = a;
            } else {
                af[rt] = *(const bf16x8*)&A1b[(size_t)ra[rt] * ldA1 + kc + g * 8];
            }
        }
        #pragma unroll
        for (int ct = 0; ct < 4; ++ct) {
            const bf16x8 bw = *(const bf16x8*)&W1t[(size_t)(ct * 16 + r16) * K1 + kc + g * 8];
            acc[0][ct] = __builtin_amdgcn_mfma_f32_16x16x32_bf16(af[0], bw, acc[0][ct], 0, 0, 0);
            acc[1][ct] = __builtin_amdgcn_mfma_f32_16x16x32_bf16(af[1], bw, acc[1][ct], 0, 0, 0);
        }
    }
    if (A2b) {
        #pragma unroll 1
        for (int kc = 0; kc < 64; kc += 32) {
            bf16x8 af[2];
            #pragma unroll
            for (int rt = 0; rt < 2; ++rt)
                af[rt] = *(const bf16x8*)&A2b[(size_t)ra[rt] * 64 + kc + g * 8];
            #pragma unroll
            for (int ct = 0; ct < 4; ++ct) {
                const bf16x8 bw = *(const bf16x8*)&W2t[(size_t)(ct * 16 + r16) * 64 + kc + g * 8];
                acc[0][ct] = __builtin_amdgcn_mfma_f32_16x16x32_bf16(af[0], bw, acc[0][ct], 0, 0, 0);
                acc[1][ct] = __builtin_amdgcn_mfma_f32_16x16x32_bf16(af[1], bw, acc[1][ct], 0, 0, 0);
            }
        }
    }

    float bcol[4];
    #pragma unroll
    for (int ct = 0; ct < 4; ++ct) bcol[ct] = bias[ct * 16 + r16];

    #pragma unroll
    for (int rt = 0; rt < 2; ++rt) {
        #pragma unroll
        for (int ct = 0; ct < 4; ++ct)
            #pragma unroll
            for (int reg = 0; reg < 4; ++reg) acc[rt][ct][reg] += bcol[ct];

        if (do_norm) {
            #pragma unroll
            for (int reg = 0; reg < 4; ++reg) {
                float ss = 0.f;
                #pragma unroll
                for (int ct = 0; ct < 4; ++ct) ss += acc[rt][ct][reg] * acc[rt][ct][reg];
                ss += __shfl_xor(ss, 1, 64);
                ss += __shfl_xor(ss, 2, 64);
                ss += __shfl_xor(ss, 4, 64);
                ss += __shfl_xor(ss, 8, 64);
                const float inv = 1.0f / fmaxf(sqrtf(ss), 1e-12f);
                #pragma unroll
                for (int ct = 0; ct < 4; ++ct)
                    acc[rt][ct][reg] = fmaxf(acc[rt][ct][reg] * inv, 0.0f);
            }
        }
    }

    if constexpr (!LAST) {
        #pragma unroll
        for (int rt = 0; rt < 2; ++rt) {
            const int rbase = row0 + rt * 16 + g * 4;
            #pragma unroll
            for (int reg = 0; reg < 4; ++reg) {
                const int rr = rbase + reg;
                if (rr < n) {
                    if (outB) {
                        #pragma unroll
                        for (int ct = 0; ct < 4; ++ct)
                            outB[(size_t)rr * 64 + ct * 16 + r16] = f2bfbits(acc[rt][ct][reg]);
                    } else {
                        #pragma unroll
                        for (int ct = 0; ct < 4; ++ct)
                            outF[(size_t)rr * 64 + ct * 16 + r16] = acc[rt][ct][reg];
                    }
                }
            }
        }
    } else {
        // stage h3 tile in LDS, then out = h3 @ W2t2 + b2 (f32)
        __shared__ unsigned short h3S[128][HSTRIDE];   // 18 KB
        #pragma unroll
        for (int rt = 0; rt < 2; ++rt) {
            #pragma unroll
            for (int reg = 0; reg < 4; ++reg) {
                const int lr = w * 32 + rt * 16 + g * 4 + reg;
                #pragma unroll
                for (int ct = 0; ct < 4; ++ct)
                    h3S[lr][ct * 16 + r16] = f2bfbits(acc[rt][ct][reg]);
            }
        }
        __syncthreads();
        f32x4 acc2[2][4];
        #pragma unroll
        for (int i = 0; i < 2; ++i)
            #pragma unroll
            for (int j = 0; j < 4; ++j) { acc2[i][j][0]=0.f; acc2[i][j][1]=0.f; acc2[i][j][2]=0.f; acc2[i][j][3]=0.f; }
        #pragma unroll
        for (int kc = 0; kc < 64; kc += 32) {
            bf16x8 af[2];
            #pragma unroll
            for (int rt = 0; rt < 2; ++rt)
                af[rt] = *(const bf16x8*)&h3S[w * 32 + rt * 16 + r16][kc + g * 8];
            #pragma unroll
            for (int ct = 0; ct < 4; ++ct) {
                const bf16x8 bw = *(const bf16x8*)&W2t2[(size_t)(ct * 16 + r16) * 64 + kc + g * 8];
                acc2[0][ct] = __builtin_amdgcn_mfma_f32_16x16x32_bf16(af[0], bw, acc2[0][ct], 0, 0, 0);
                acc2[1][ct] = __builtin_amdgcn_mfma_f32_16x16x32_bf16(af[1], bw, acc2[1][ct], 0, 0, 0);
            }
        }
        float b2c[4];
        #pragma unroll
        for (int ct = 0; ct < 4; ++ct) b2c[ct] = b2[ct * 16 + r16];
        #pragma unroll
        for (int rt = 0; rt < 2; ++rt) {
            const int rbase = row0 + rt * 16 + g * 4;
            #pragma unroll
            for (int reg = 0; reg < 4; ++reg) {
                const int rr = rbase + reg;
                if (rr < n) {
                    #pragma unroll
                    for (int ct = 0; ct < 4; ++ct)
                        outF[(size_t)rr * 64 + ct * 16 + r16] = acc2[rt][ct][reg] + b2c[ct];
                }
            }
        }
    }
}

// ---------------- launch ----------------

extern "C" void kernel_launch(void* const* d_in, const int* in_sizes, int n_in,
                              void* d_out, int out_size, void* d_ws, size_t ws_size,
                              hipStream_t stream) {
    const float* x  = (const float*)d_in[0];
    const int*   ei = (const int*)  d_in[1];
    const float* W1 = (const float*)d_in[2];
    const float* b1 = (const float*)d_in[3];
    const float* Wl = (const float*)d_in[4];
    const float* bl = (const float*)d_in[5];
    const float* Wr = (const float*)d_in[6];
    const float* W2 = (const float*)d_in[7];
    const float* b2 = (const float*)d_in[8];
    float* out = (float*)d_out;

    const int n = in_sizes[0] / 128;   // 100000
    const int m = in_sizes[1] / 2;     // 1250000
    const int* src = ei;
    const int* dst = ei + m;

    const int nsb = (n + 511) >> 9;    // 196 super-buckets (<= 256)

    char* ws = (char*)d_ws;
    size_t off = 0;
    auto alloc = [&](size_t bytes) -> void* {
        void* p = ws + off;
        off = (off + bytes + 255) & ~(size_t)255;
        return p;
    };
    unsigned short* aggB    = (unsigned short*)alloc((size_t)n * 64 * 2);
    unsigned short* hbf     = (unsigned short*)alloc((size_t)n * 64 * 2);
    int*            row_ptr = (int*)alloc((size_t)(n + 1) * sizeof(int));
    unsigned*       gcur    = (unsigned*)alloc((size_t)nsb * 4);
    unsigned*       bins    = (unsigned*)alloc((size_t)nsb * SBCAP * 4);
    int*            csr     = (int*)alloc((size_t)m * 4);
    unsigned short* wt      = (unsigned short*)alloc(36864 * 2);

    const unsigned short* W1t = wt;
    const unsigned short* W2t = wt + 32768;

    const int nb1 = (m + BATCH - 1) / BATCH;   // 306
    const int gtiles = (n + 127) / 128;        // 782

    wconv_kernel<<<144, NT, 0, stream>>>(W1, Wl, Wr, W2, wt, gcur, nsb);

    // h0 = x @ W1 + b1 -> hbf (bf16)
    gemm_mfma<1, 0><<<gtiles, NT, 0, stream>>>(x, nullptr, 128, 128, W1t,
                                               nullptr, nullptr, b1, nullptr, hbf, n, 0,
                                               nullptr, nullptr);

    // two-level binned CSR build
    bin1_kernel<<<nb1, NT, 0, stream>>>(src, dst, m, gcur, bins);
    bin2_kernel<<<nsb, NT, 0, stream>>>(bins, gcur, row_ptr, csr, n, nsb, m);

    // layers 1,2: agg + GEMM(norm,relu), h in-place; layer 3: GEMM also applies W2 -> out
    for (int i = 0; i < 2; ++i) {
        agg_kernel<<<2048, NT, 0, stream>>>(hbf, row_ptr, csr, aggB, n);
        const unsigned short* Wlt = wt + 8192 + (size_t)i * 8192;
        const unsigned short* Wrt = Wlt + 4096;
        gemm_mfma<0, 0><<<gtiles, NT, 0, stream>>>(nullptr, aggB, 64, 64, Wlt,
                                                   hbf, Wrt, bl + (size_t)i * 64,
                                                   nullptr, hbf, n, 1, nullptr, nullptr);
    }
    agg_kernel<<<2048, NT, 0, stream>>>(hbf, row_ptr, csr, aggB, n);
    gemm_mfma<0, 1><<<gtiles, NT, 0, stream>>>(nullptr, aggB, 64, 64, wt + 8192 + 16384,
                                               hbf, wt + 8192 + 16384 + 4096, bl + 128,
                                               out, nullptr, n, 1, W2t, b2);
}

// Round 15
// 197.954 us; speedup vs baseline: 1.7431x; 1.0327x over previous
//
#include <hip/hip_runtime.h>
#include <hip/hip_bf16.h>

// GraphSAGE forward (R15 = R14 + clamped-batch MLP agg):
//   bin1 -> bin2 (inline base scan) -> wconv(+gcur zero) -> lin1 (MFMA) ->
//   3x [agg (half-wave/node, 8 clamped loads in flight) + MFMA GEMM(norm,relu)];
//   layer-3 GEMM also applies W2 -> f32 out. h row-major bf16 [n][64].

#define NT 256
#define BATCH 4096        // edges per bin1 block (NT * 16)
#define SBCAP 8192        // slots per super-bucket region (mean 6378 for m=1.25M)
#define HSTRIDE 72        // h3 LDS tile row stride (bf16)

typedef __attribute__((ext_vector_type(8))) short bf16x8;
typedef __attribute__((ext_vector_type(4))) float f32x4;

__device__ __forceinline__ float bfbits2f(unsigned short b) {
    return __uint_as_float(((unsigned)b) << 16);
}
__device__ __forceinline__ unsigned short f2bfbits(float v) {
    __hip_bfloat16 b = __float2bfloat16(v);
    return *reinterpret_cast<unsigned short*>(&b);
}

// ---------------- CSR build: two-level binning ----------------

__global__ __launch_bounds__(NT) void bin1_kernel(const int* __restrict__ src,
    const int* __restrict__ dst, int m, unsigned* __restrict__ gcur,
    unsigned* __restrict__ bins) {
    __shared__ unsigned hist[256];
    __shared__ unsigned gbase[256];
    const int t = threadIdx.x;
    const int base = blockIdx.x * BATCH;
    hist[t] = 0;
    __syncthreads();
    int d[16], s[16];
    const int e0 = base + t * 16;
    const bool full = (base + BATCH) <= m;
    if (full) {
        #pragma unroll
        for (int q = 0; q < 4; ++q) {
            const int4 dv = *(const int4*)&dst[e0 + q * 4];
            const int4 sv = *(const int4*)&src[e0 + q * 4];
            d[q*4+0]=dv.x; d[q*4+1]=dv.y; d[q*4+2]=dv.z; d[q*4+3]=dv.w;
            s[q*4+0]=sv.x; s[q*4+1]=sv.y; s[q*4+2]=sv.z; s[q*4+3]=sv.w;
        }
        #pragma unroll
        for (int q = 0; q < 16; ++q) atomicAdd(&hist[d[q] >> 9], 1u);
    } else {
        #pragma unroll
        for (int q = 0; q < 16; ++q) {
            const int e = e0 + q;
            if (e < m) { d[q] = dst[e]; s[q] = src[e]; atomicAdd(&hist[d[q] >> 9], 1u); }
            else d[q] = -1;
        }
    }
    __syncthreads();
    {
        const unsigned h = hist[t];
        gbase[t] = h ? atomicAdd(&gcur[t], h) : 0u;
        hist[t] = 0;                       // reuse as per-bucket cursor
    }
    __syncthreads();
    if (full) {
        #pragma unroll
        for (int q = 0; q < 16; ++q) {
            const int b = d[q] >> 9;
            const unsigned slot = gbase[b] + atomicAdd(&hist[b], 1u);
            bins[(size_t)b * SBCAP + slot] = ((unsigned)s[q] << 9) | (unsigned)(d[q] & 511);
        }
    } else {
        #pragma unroll
        for (int q = 0; q < 16; ++q) {
            if (d[q] >= 0) {
                const int b = d[q] >> 9;
                const unsigned slot = gbase[b] + atomicAdd(&hist[b], 1u);
                bins[(size_t)b * SBCAP + slot] = ((unsigned)s[q] << 9) | (unsigned)(d[q] & 511);
            }
        }
    }
}

// bin2: per super-bucket; computes its own base by scanning gcur (<=256 words) in-block.
__global__ __launch_bounds__(NT) void bin2_kernel(const unsigned* __restrict__ bins,
    const unsigned* __restrict__ gcur, int* __restrict__ row_ptr, int* __restrict__ csr,
    int n, int nsb, int m) {
    __shared__ unsigned hist[512];
    __shared__ unsigned off[512];
    __shared__ unsigned cur[512];
    __shared__ unsigned wsum[4];
    __shared__ unsigned gpre[256];
    const int k = blockIdx.x;
    const int t = threadIdx.x;
    const int lane = t & 63, wid = t >> 6;

    {
        const unsigned gv = (t < nsb) ? gcur[t] : 0u;
        unsigned gx = gv;
        #pragma unroll
        for (int o = 1; o < 64; o <<= 1) {
            const unsigned tt = __shfl_up(gx, o, 64);
            if (lane >= o) gx += tt;
        }
        if (lane == 63) wsum[wid] = gx;
        __syncthreads();
        unsigned wo = 0;
        for (int w = 0; w < wid; ++w) wo += wsum[w];
        gpre[t] = wo + gx - gv;
        __syncthreads();
    }
    const int cnt = (int)gcur[k];
    const unsigned sb = gpre[k];
    if (k == 0 && t == 0) row_ptr[n] = m;

    const unsigned* reg = bins + (size_t)k * SBCAP;
    hist[2*t] = 0; hist[2*t+1] = 0;
    __syncthreads();
    for (int i = t; i < cnt; i += NT) atomicAdd(&hist[reg[i] & 511u], 1u);
    __syncthreads();
    const unsigned v0 = hist[2*t], v1 = hist[2*t+1];
    const unsigned ps = v0 + v1;
    unsigned x = ps;
    #pragma unroll
    for (int o = 1; o < 64; o <<= 1) {
        const unsigned tt = __shfl_up(x, o, 64);
        if (lane >= o) x += tt;
    }
    if (lane == 63) wsum[wid] = x;
    __syncthreads();
    unsigned woff = 0;
    for (int w = 0; w < wid; ++w) woff += wsum[w];
    const unsigned excl = woff + x - ps;
    off[2*t] = excl; off[2*t+1] = excl + v0;
    cur[2*t] = 0; cur[2*t+1] = 0;
    const int node = k * 512 + 2 * t;
    if (node < n)     row_ptr[node]     = (int)(sb + excl);
    if (node + 1 < n) row_ptr[node + 1] = (int)(sb + excl + v0);
    __syncthreads();
    for (int i = t; i < cnt; i += NT) {
        const unsigned u = reg[i];
        const unsigned l = u & 511u;
        const unsigned r = atomicAdd(&cur[l], 1u);
        csr[sb + off[l] + r] = (int)(u >> 9);
    }
}

// ---------------- weight convert+transpose (+ gcur zeroing): Wt[col][k] bf16 ----------------

__global__ void wconv_kernel(const float* __restrict__ W1, const float* __restrict__ Wl,
                             const float* __restrict__ Wr, const float* __restrict__ W2,
                             unsigned short* __restrict__ out, unsigned* __restrict__ gcur,
                             int nsb) {
    int i = blockIdx.x * blockDim.x + threadIdx.x;
    if (i < nsb) gcur[i] = 0u;
    if (i >= 36864) return;
    float v;
    if (i < 8192) {
        const int col = i >> 7, k = i & 127;
        v = W1[k * 64 + col];
    } else if (i < 32768) {
        const int j = i - 8192;
        const int mm = j >> 13, r = j & 8191;
        const int isR = (r >> 12) & 1, q = r & 4095;
        const int col = q >> 6, k = q & 63;
        v = (isR ? Wr : Wl)[mm * 4096 + k * 64 + col];
    } else {
        const int q = i - 32768;
        const int col = q >> 6, k = q & 63;
        v = W2[k * 64 + col];
    }
    out[i] = f2bfbits(v);
}

// ---------------- aggregation: 2 nodes/wave, clamped-batch loads for full MLP ----------------
// half = lane>>5 -> node 2p+half; gs = (lane>>4)&1 (2 edge slots); c = lane&15 (ushort4).
// Batch 1: 8 clamped loads (16 edges) all issued back-to-back; overflow (deg>16) in
// clamped 4-load batches. Invalid slots read csr[0]/h[...] harmlessly, masked on accumulate.

__global__ __launch_bounds__(NT) void agg_kernel(const unsigned short* __restrict__ h,
    const int* __restrict__ row_ptr, const int* __restrict__ csr,
    unsigned short* __restrict__ aggB, int n) {
    const int t = threadIdx.x;
    const int lane = t & 63;
    const int half = lane >> 5;
    const int gs = (lane >> 4) & 1;
    const int c = lane & 15;
    const int gw = (blockIdx.x * NT + t) >> 6;
    const int nw = (gridDim.x * NT) >> 6;
    const int npairs = (n + 1) >> 1;
    for (int p = gw; p < npairs; p += nw) {
        const int node = p * 2 + half;
        const bool valid = node < n;
        const int node_c = valid ? node : (n - 1);
        const int rs = row_ptr[node_c];
        const int re = row_ptr[node_c + 1];
        float a0 = 0.f, a1 = 0.f, a2 = 0.f, a3 = 0.f;
        {
            int ce[8], si[8];
            #pragma unroll
            for (int i = 0; i < 8; ++i) {
                const int e = rs + 2 * i + gs;
                ce[i] = (e < re) ? e : 0;
            }
            #pragma unroll
            for (int i = 0; i < 8; ++i) si[i] = csr[ce[i]];
            ushort4 v[8];
            #pragma unroll
            for (int i = 0; i < 8; ++i) v[i] = *(const ushort4*)&h[(size_t)si[i] * 64 + c * 4];
            #pragma unroll
            for (int i = 0; i < 8; ++i) {
                if (rs + 2 * i + gs < re) {
                    a0 += bfbits2f(v[i].x);
                    a1 += bfbits2f(v[i].y);
                    a2 += bfbits2f(v[i].z);
                    a3 += bfbits2f(v[i].w);
                }
            }
        }
        // overflow: edges beyond the first 16 (deg > 16, ~12% of nodes)
        for (int base = rs + 16; base < re; base += 8) {
            int ce[4], si[4];
            #pragma unroll
            for (int i = 0; i < 4; ++i) {
                const int e = base + 2 * i + gs;
                ce[i] = (e < re) ? e : 0;
            }
            #pragma unroll
            for (int i = 0; i < 4; ++i) si[i] = csr[ce[i]];
            ushort4 v[4];
            #pragma unroll
            for (int i = 0; i < 4; ++i) v[i] = *(const ushort4*)&h[(size_t)si[i] * 64 + c * 4];
            #pragma unroll
            for (int i = 0; i < 4; ++i) {
                if (base + 2 * i + gs < re) {
                    a0 += bfbits2f(v[i].x);
                    a1 += bfbits2f(v[i].y);
                    a2 += bfbits2f(v[i].z);
                    a3 += bfbits2f(v[i].w);
                }
            }
        }
        // reduce across the 2 edge slots (lane bit 4; stays within each half)
        a0 += __shfl_xor(a0, 16, 64);
        a1 += __shfl_xor(a1, 16, 64);
        a2 += __shfl_xor(a2, 16, 64);
        a3 += __shfl_xor(a3, 16, 64);
        if (gs == 0 && valid) {
            const float inv = (re > rs) ? (1.0f / (float)(re - rs)) : 0.0f;
            ushort4 o;
            o.x = f2bfbits(a0 * inv);
            o.y = f2bfbits(a1 * inv);
            o.z = f2bfbits(a2 * inv);
            o.w = f2bfbits(a3 * inv);
            *(ushort4*)&aggB[(size_t)node * 64 + c * 4] = o;
        }
    }
}

// ---------------- MFMA GEMM: C = A1@W1 [+ A2@W2] + bias; optional norm; LAST: + (C@W2t2 + b2) ----------------
// block = 4 waves, wave = 32 rows x 64 cols (2 row-tiles x 4 col-tiles of 16x16x32 mfma).
// C/D: col = lane&15, row = (lane>>4)*4 + reg.

template<int A1F32, int LAST>
__global__ __launch_bounds__(NT) void gemm_mfma(
    const float* __restrict__ A1f, const unsigned short* __restrict__ A1b,
    int ldA1, int K1, const unsigned short* __restrict__ W1t,
    const unsigned short* __restrict__ A2b, const unsigned short* __restrict__ W2t,
    const float* __restrict__ bias, float* __restrict__ outF,
    unsigned short* __restrict__ outB, int n, int do_norm,
    const unsigned short* __restrict__ W2t2, const float* __restrict__ b2) {
    const int t = threadIdx.x;
    const int lane = t & 63;
    const int w = t >> 6;
    const int r16 = lane & 15;
    const int g = lane >> 4;
    const int row0 = blockIdx.x * 128 + w * 32;

    f32x4 acc[2][4];
    #pragma unroll
    for (int i = 0; i < 2; ++i)
        #pragma unroll
        for (int j = 0; j < 4; ++j) {
            acc[i][j][0] = 0.f; acc[i][j][1] = 0.f; acc[i][j][2] = 0.f; acc[i][j][3] = 0.f;
        }

    int ra[2];
    #pragma unroll
    for (int rt = 0; rt < 2; ++rt) {
        int r = row0 + rt * 16 + r16;
        ra[rt] = (r < n) ? r : (n - 1);
    }

    #pragma unroll 1
    for (int kc = 0; kc < K1; kc += 32) {
        bf16x8 af[2];
        #pragma unroll
        for (int rt = 0; rt < 2; ++rt) {
            if (A1F32) {
                const float* p = &A1f[(size_t)ra[rt] * ldA1 + kc + g * 8];
                const float4 f0 = *(const float4*)p;
                const float4 f1 = *(const float4*)(p + 4);
                bf16x8 a;
                a[0] = (short)f2bfbits(f0.x); a[1] = (short)f2bfbits(f0.y);
                a[2] = (short)f2bfbits(f0.z); a[3] = (short)f2bfbits(f0.w);
                a[4] = (short)f2bfbits(f1.x); a[5] = (short)f2bfbits(f1.y);
                a[6] = (short)f2bfbits(f1.z); a[7] = (short)f2bfbits(f1.w);
                af[rt] = a;
            } else {
                af[rt] = *(const bf16x8*)&A1b[(size_t)ra[rt] * ldA1 + kc + g * 8];
            }
        }
        #pragma unroll
        for (int ct = 0; ct < 4; ++ct) {
            const bf16x8 bw = *(const bf16x8*)&W1t[(size_t)(ct * 16 + r16) * K1 + kc + g * 8];
            acc[0][ct] = __builtin_amdgcn_mfma_f32_16x16x32_bf16(af[0], bw, acc[0][ct], 0, 0, 0);
            acc[1][ct] = __builtin_amdgcn_mfma_f32_16x16x32_bf16(af[1], bw, acc[1][ct], 0, 0, 0);
        }
    }
    if (A2b) {
        #pragma unroll 1
        for (int kc = 0; kc < 64; kc += 32) {
            bf16x8 af[2];
            #pragma unroll
            for (int rt = 0; rt < 2; ++rt)
                af[rt] = *(const bf16x8*)&A2b[(size_t)ra[rt] * 64 + kc + g * 8];
            #pragma unroll
            for (int ct = 0; ct < 4; ++ct) {
                const bf16x8 bw = *(const bf16x8*)&W2t[(size_t)(ct * 16 + r16) * 64 + kc + g * 8];
                acc[0][ct] = __builtin_amdgcn_mfma_f32_16x16x32_bf16(af[0], bw, acc[0][ct], 0, 0, 0);
                acc[1][ct] = __builtin_amdgcn_mfma_f32_16x16x32_bf16(af[1], bw, acc[1][ct], 0, 0, 0);
            }
        }
    }

    float bcol[4];
    #pragma unroll
    for (int ct = 0; ct < 4; ++ct) bcol[ct] = bias[ct * 16 + r16];

    #pragma unroll
    for (int rt = 0; rt < 2; ++rt) {
        #pragma unroll
        for (int ct = 0; ct < 4; ++ct)
            #pragma unroll
            for (int reg = 0; reg < 4; ++reg) acc[rt][ct][reg] += bcol[ct];

        if (do_norm) {
            #pragma unroll
            for (int reg = 0; reg < 4; ++reg) {
                float ss = 0.f;
                #pragma unroll
                for (int ct = 0; ct < 4; ++ct) ss += acc[rt][ct][reg] * acc[rt][ct][reg];
                ss += __shfl_xor(ss, 1, 64);
                ss += __shfl_xor(ss, 2, 64);
                ss += __shfl_xor(ss, 4, 64);
                ss += __shfl_xor(ss, 8, 64);
                const float inv = 1.0f / fmaxf(sqrtf(ss), 1e-12f);
                #pragma unroll
                for (int ct = 0; ct < 4; ++ct)
                    acc[rt][ct][reg] = fmaxf(acc[rt][ct][reg] * inv, 0.0f);
            }
        }
    }

    if constexpr (!LAST) {
        #pragma unroll
        for (int rt = 0; rt < 2; ++rt) {
            const int rbase = row0 + rt * 16 + g * 4;
            #pragma unroll
            for (int reg = 0; reg < 4; ++reg) {
                const int rr = rbase + reg;
                if (rr < n) {
                    if (outB) {
                        #pragma unroll
                        for (int ct = 0; ct < 4; ++ct)
                            outB[(size_t)rr * 64 + ct * 16 + r16] = f2bfbits(acc[rt][ct][reg]);
                    } else {
                        #pragma unroll
                        for (int ct = 0; ct < 4; ++ct)
                            outF[(size_t)rr * 64 + ct * 16 + r16] = acc[rt][ct][reg];
                    }
                }
            }
        }
    } else {
        // stage h3 tile in LDS, then out = h3 @ W2t2 + b2 (f32)
        __shared__ unsigned short h3S[128][HSTRIDE];   // 18 KB
        #pragma unroll
        for (int rt = 0; rt < 2; ++rt) {
            #pragma unroll
            for (int reg = 0; reg < 4; ++reg) {
                const int lr = w * 32 + rt * 16 + g * 4 + reg;
                #pragma unroll
                for (int ct = 0; ct < 4; ++ct)
                    h3S[lr][ct * 16 + r16] = f2bfbits(acc[rt][ct][reg]);
            }
        }
        __syncthreads();
        f32x4 acc2[2][4];
        #pragma unroll
        for (int i = 0; i < 2; ++i)
            #pragma unroll
            for (int j = 0; j < 4; ++j) { acc2[i][j][0]=0.f; acc2[i][j][1]=0.f; acc2[i][j][2]=0.f; acc2[i][j][3]=0.f; }
        #pragma unroll
        for (int kc = 0; kc < 64; kc += 32) {
            bf16x8 af[2];
            #pragma unroll
            for (int rt = 0; rt < 2; ++rt)
                af[rt] = *(const bf16x8*)&h3S[w * 32 + rt * 16 + r16][kc + g * 8];
            #pragma unroll
            for (int ct = 0; ct < 4; ++ct) {
                const bf16x8 bw = *(const bf16x8*)&W2t2[(size_t)(ct * 16 + r16) * 64 + kc + g * 8];
                acc2[0][ct] = __builtin_amdgcn_mfma_f32_16x16x32_bf16(af[0], bw, acc2[0][ct], 0, 0, 0);
                acc2[1][ct] = __builtin_amdgcn_mfma_f32_16x16x32_bf16(af[1], bw, acc2[1][ct], 0, 0, 0);
            }
        }
        float b2c[4];
        #pragma unroll
        for (int ct = 0; ct < 4; ++ct) b2c[ct] = b2[ct * 16 + r16];
        #pragma unroll
        for (int rt = 0; rt < 2; ++rt) {
            const int rbase = row0 + rt * 16 + g * 4;
            #pragma unroll
            for (int reg = 0; reg < 4; ++reg) {
                const int rr = rbase + reg;
                if (rr < n) {
                    #pragma unroll
                    for (int ct = 0; ct < 4; ++ct)
                        outF[(size_t)rr * 64 + ct * 16 + r16] = acc2[rt][ct][reg] + b2c[ct];
                }
            }
        }
    }
}

// ---------------- launch ----------------

extern "C" void kernel_launch(void* const* d_in, const int* in_sizes, int n_in,
                              void* d_out, int out_size, void* d_ws, size_t ws_size,
                              hipStream_t stream) {
    const float* x  = (const float*)d_in[0];
    const int*   ei = (const int*)  d_in[1];
    const float* W1 = (const float*)d_in[2];
    const float* b1 = (const float*)d_in[3];
    const float* Wl = (const float*)d_in[4];
    const float* bl = (const float*)d_in[5];
    const float* Wr = (const float*)d_in[6];
    const float* W2 = (const float*)d_in[7];
    const float* b2 = (const float*)d_in[8];
    float* out = (float*)d_out;

    const int n = in_sizes[0] / 128;   // 100000
    const int m = in_sizes[1] / 2;     // 1250000
    const int* src = ei;
    const int* dst = ei + m;

    const int nsb = (n + 511) >> 9;    // 196 super-buckets (<= 256)

    char* ws = (char*)d_ws;
    size_t off = 0;
    auto alloc = [&](size_t bytes) -> void* {
        void* p = ws + off;
        off = (off + bytes + 255) & ~(size_t)255;
        return p;
    };
    unsigned short* aggB    = (unsigned short*)alloc((size_t)n * 64 * 2);
    unsigned short* hbf     = (unsigned short*)alloc((size_t)n * 64 * 2);
    int*            row_ptr = (int*)alloc((size_t)(n + 1) * sizeof(int));
    unsigned*       gcur    = (unsigned*)alloc((size_t)nsb * 4);
    unsigned*       bins    = (unsigned*)alloc((size_t)nsb * SBCAP * 4);
    int*            csr     = (int*)alloc((size_t)m * 4);
    unsigned short* wt      = (unsigned short*)alloc(36864 * 2);

    const unsigned short* W1t = wt;
    const unsigned short* W2t = wt + 32768;

    const int nb1 = (m + BATCH - 1) / BATCH;   // 306
    const int gtiles = (n + 127) / 128;        // 782

    wconv_kernel<<<144, NT, 0, stream>>>(W1, Wl, Wr, W2, wt, gcur, nsb);

    // h0 = x @ W1 + b1 -> hbf (bf16)
    gemm_mfma<1, 0><<<gtiles, NT, 0, stream>>>(x, nullptr, 128, 128, W1t,
                                               nullptr, nullptr, b1, nullptr, hbf, n, 0,
                                               nullptr, nullptr);

    // two-level binned CSR build
    bin1_kernel<<<nb1, NT, 0, stream>>>(src, dst, m, gcur, bins);
    bin2_kernel<<<nsb, NT, 0, stream>>>(bins, gcur, row_ptr, csr, n, nsb, m);

    // layers 1,2: agg + GEMM(norm,relu), h in-place; layer 3: GEMM also applies W2 -> out
    for (int i = 0; i < 2; ++i) {
        agg_kernel<<<2048, NT, 0, stream>>>(hbf, row_ptr, csr, aggB, n);
        const unsigned short* Wlt = wt + 8192 + (size_t)i * 8192;
        const unsigned short* Wrt = Wlt + 4096;
        gemm_mfma<0, 0><<<gtiles, NT, 0, stream>>>(nullptr, aggB, 64, 64, Wlt,
                                                   hbf, Wrt, bl + (size_t)i * 64,
                                                   nullptr, hbf, n, 1, nullptr, nullptr);
    }
    agg_kernel<<<2048, NT, 0, stream>>>(hbf, row_ptr, csr, aggB, n);
    gemm_mfma<0, 1><<<gtiles, NT, 0, stream>>>(nullptr, aggB, 64, 64, wt + 8192 + 16384,
                                               hbf, wt + 8192 + 16384 + 4096, bl + 128,
                                               out, nullptr, n, 1, W2t, b2);
}

// Round 16
// 188.391 us; speedup vs baseline: 1.8316x; 1.0508x over previous
//
#include <hip/hip_runtime.h>
#include <hip/hip_bf16.h>

// GraphSAGE forward (R16 = R15 + block-range fusion of independent phases):
//   memset(gcur) -> [wconv || bin1] -> [bin2 || lin1] ->
//   3x [agg (half-wave/node, clamped-batch MLP) + MFMA GEMM(norm,relu)];
//   layer-3 GEMM also applies W2 -> f32 out. h row-major bf16 [n][64].

#define NT 256
#define BATCH 4096        // edges per bin1 block (NT * 16)
#define SBCAP 8192        // slots per super-bucket region (mean 6378 for m=1.25M)
#define HSTRIDE 72        // h3 LDS tile row stride (bf16)
#define WCONV_BLOCKS 144

typedef __attribute__((ext_vector_type(8))) short bf16x8;
typedef __attribute__((ext_vector_type(4))) float f32x4;

__device__ __forceinline__ float bfbits2f(unsigned short b) {
    return __uint_as_float(((unsigned)b) << 16);
}
__device__ __forceinline__ unsigned short f2bfbits(float v) {
    __hip_bfloat16 b = __float2bfloat16(v);
    return *reinterpret_cast<unsigned short*>(&b);
}

// ---------------- fused kernel A: wconv (blocks 0..143) || bin1 (blocks 144..) ----------------

__global__ __launch_bounds__(NT) void wconv_bin1_kernel(
    const float* __restrict__ W1, const float* __restrict__ Wl,
    const float* __restrict__ Wr, const float* __restrict__ W2,
    unsigned short* __restrict__ wt,
    const int* __restrict__ src, const int* __restrict__ dst, int m,
    unsigned* __restrict__ gcur, unsigned* __restrict__ bins) {
    const int t = threadIdx.x;
    if ((int)blockIdx.x < WCONV_BLOCKS) {
        const int i = blockIdx.x * NT + t;
        if (i >= 36864) return;
        float v;
        if (i < 8192) {
            const int col = i >> 7, k = i & 127;
            v = W1[k * 64 + col];
        } else if (i < 32768) {
            const int j = i - 8192;
            const int mm = j >> 13, r = j & 8191;
            const int isR = (r >> 12) & 1, q = r & 4095;
            const int col = q >> 6, k = q & 63;
            v = (isR ? Wr : Wl)[mm * 4096 + k * 64 + col];
        } else {
            const int q = i - 32768;
            const int col = q >> 6, k = q & 63;
            v = W2[k * 64 + col];
        }
        wt[i] = f2bfbits(v);
        return;
    }
    // ---- bin1 ----
    __shared__ unsigned hist[256];
    __shared__ unsigned gbase[256];
    const int bb = (int)blockIdx.x - WCONV_BLOCKS;
    const int base = bb * BATCH;
    hist[t] = 0;
    __syncthreads();
    int d[16], s[16];
    const int e0 = base + t * 16;
    const bool full = (base + BATCH) <= m;
    if (full) {
        #pragma unroll
        for (int q = 0; q < 4; ++q) {
            const int4 dv = *(const int4*)&dst[e0 + q * 4];
            const int4 sv = *(const int4*)&src[e0 + q * 4];
            d[q*4+0]=dv.x; d[q*4+1]=dv.y; d[q*4+2]=dv.z; d[q*4+3]=dv.w;
            s[q*4+0]=sv.x; s[q*4+1]=sv.y; s[q*4+2]=sv.z; s[q*4+3]=sv.w;
        }
        #pragma unroll
        for (int q = 0; q < 16; ++q) atomicAdd(&hist[d[q] >> 9], 1u);
    } else {
        #pragma unroll
        for (int q = 0; q < 16; ++q) {
            const int e = e0 + q;
            if (e < m) { d[q] = dst[e]; s[q] = src[e]; atomicAdd(&hist[d[q] >> 9], 1u); }
            else d[q] = -1;
        }
    }
    __syncthreads();
    {
        const unsigned h = hist[t];
        gbase[t] = h ? atomicAdd(&gcur[t], h) : 0u;
        hist[t] = 0;                       // reuse as per-bucket cursor
    }
    __syncthreads();
    if (full) {
        #pragma unroll
        for (int q = 0; q < 16; ++q) {
            const int b = d[q] >> 9;
            const unsigned slot = gbase[b] + atomicAdd(&hist[b], 1u);
            bins[(size_t)b * SBCAP + slot] = ((unsigned)s[q] << 9) | (unsigned)(d[q] & 511);
        }
    } else {
        #pragma unroll
        for (int q = 0; q < 16; ++q) {
            if (d[q] >= 0) {
                const int b = d[q] >> 9;
                const unsigned slot = gbase[b] + atomicAdd(&hist[b], 1u);
                bins[(size_t)b * SBCAP + slot] = ((unsigned)s[q] << 9) | (unsigned)(d[q] & 511);
            }
        }
    }
}

// ---------------- fused kernel B: bin2 (blocks 0..nsb-1) || lin1 (rest) ----------------

__device__ __forceinline__ void lin1_body(const float* __restrict__ x,
    const unsigned short* __restrict__ W1t, const float* __restrict__ b1,
    unsigned short* __restrict__ hbf, int n, int bid) {
    const int t = threadIdx.x;
    const int lane = t & 63;
    const int w = t >> 6;
    const int r16 = lane & 15;
    const int g = lane >> 4;
    const int row0 = bid * 128 + w * 32;

    f32x4 acc[2][4];
    #pragma unroll
    for (int i = 0; i < 2; ++i)
        #pragma unroll
        for (int j = 0; j < 4; ++j) { acc[i][j][0]=0.f; acc[i][j][1]=0.f; acc[i][j][2]=0.f; acc[i][j][3]=0.f; }

    int ra[2];
    #pragma unroll
    for (int rt = 0; rt < 2; ++rt) {
        const int r = row0 + rt * 16 + r16;
        ra[rt] = (r < n) ? r : (n - 1);
    }

    #pragma unroll 1
    for (int kc = 0; kc < 128; kc += 32) {
        bf16x8 af[2];
        #pragma unroll
        for (int rt = 0; rt < 2; ++rt) {
            const float* p = &x[(size_t)ra[rt] * 128 + kc + g * 8];
            const float4 f0 = *(const float4*)p;
            const float4 f1 = *(const float4*)(p + 4);
            bf16x8 a;
            a[0] = (short)f2bfbits(f0.x); a[1] = (short)f2bfbits(f0.y);
            a[2] = (short)f2bfbits(f0.z); a[3] = (short)f2bfbits(f0.w);
            a[4] = (short)f2bfbits(f1.x); a[5] = (short)f2bfbits(f1.y);
            a[6] = (short)f2bfbits(f1.z); a[7] = (short)f2bfbits(f1.w);
            af[rt] = a;
        }
        #pragma unroll
        for (int ct = 0; ct < 4; ++ct) {
            const bf16x8 bw = *(const bf16x8*)&W1t[(size_t)(ct * 16 + r16) * 128 + kc + g * 8];
            acc[0][ct] = __builtin_amdgcn_mfma_f32_16x16x32_bf16(af[0], bw, acc[0][ct], 0, 0, 0);
            acc[1][ct] = __builtin_amdgcn_mfma_f32_16x16x32_bf16(af[1], bw, acc[1][ct], 0, 0, 0);
        }
    }

    float bcol[4];
    #pragma unroll
    for (int ct = 0; ct < 4; ++ct) bcol[ct] = b1[ct * 16 + r16];
    #pragma unroll
    for (int rt = 0; rt < 2; ++rt) {
        const int rbase = row0 + rt * 16 + g * 4;
        #pragma unroll
        for (int reg = 0; reg < 4; ++reg) {
            const int rr = rbase + reg;
            if (rr < n) {
                #pragma unroll
                for (int ct = 0; ct < 4; ++ct)
                    hbf[(size_t)rr * 64 + ct * 16 + r16] = f2bfbits(acc[rt][ct][reg] + bcol[ct]);
            }
        }
    }
}

__global__ __launch_bounds__(NT) void bin2_lin1_kernel(
    const unsigned* __restrict__ bins, const unsigned* __restrict__ gcur,
    int* __restrict__ row_ptr, int* __restrict__ csr, int n, int nsb, int m,
    const float* __restrict__ x, const unsigned short* __restrict__ W1t,
    const float* __restrict__ b1, unsigned short* __restrict__ hbf) {
    __shared__ unsigned hist[512];
    __shared__ unsigned off[512];
    __shared__ unsigned cur[512];
    __shared__ unsigned wsum[4];
    __shared__ unsigned gpre[256];
    const int t = threadIdx.x;
    if ((int)blockIdx.x >= nsb) {
        lin1_body(x, W1t, b1, hbf, n, (int)blockIdx.x - nsb);
        return;
    }
    const int k = blockIdx.x;
    const int lane = t & 63, wid = t >> 6;

    {
        const unsigned gv = (t < nsb) ? gcur[t] : 0u;
        unsigned gx = gv;
        #pragma unroll
        for (int o = 1; o < 64; o <<= 1) {
            const unsigned tt = __shfl_up(gx, o, 64);
            if (lane >= o) gx += tt;
        }
        if (lane == 63) wsum[wid] = gx;
        __syncthreads();
        unsigned wo = 0;
        for (int w = 0; w < wid; ++w) wo += wsum[w];
        gpre[t] = wo + gx - gv;
        __syncthreads();
    }
    const int cnt = (int)gcur[k];
    const unsigned sb = gpre[k];
    if (k == 0 && t == 0) row_ptr[n] = m;

    const unsigned* reg = bins + (size_t)k * SBCAP;
    hist[2*t] = 0; hist[2*t+1] = 0;
    __syncthreads();
    for (int i = t; i < cnt; i += NT) atomicAdd(&hist[reg[i] & 511u], 1u);
    __syncthreads();
    const unsigned v0 = hist[2*t], v1 = hist[2*t+1];
    const unsigned ps = v0 + v1;
    unsigned x2 = ps;
    #pragma unroll
    for (int o = 1; o < 64; o <<= 1) {
        const unsigned tt = __shfl_up(x2, o, 64);
        if (lane >= o) x2 += tt;
    }
    if (lane == 63) wsum[wid] = x2;
    __syncthreads();
    unsigned woff = 0;
    for (int w = 0; w < wid; ++w) woff += wsum[w];
    const unsigned excl = woff + x2 - ps;
    off[2*t] = excl; off[2*t+1] = excl + v0;
    cur[2*t] = 0; cur[2*t+1] = 0;
    const int node = k * 512 + 2 * t;
    if (node < n)     row_ptr[node]     = (int)(sb + excl);
    if (node + 1 < n) row_ptr[node + 1] = (int)(sb + excl + v0);
    __syncthreads();
    for (int i = t; i < cnt; i += NT) {
        const unsigned u = reg[i];
        const unsigned l = u & 511u;
        const unsigned r = atomicAdd(&cur[l], 1u);
        csr[sb + off[l] + r] = (int)(u >> 9);
    }
}

// ---------------- aggregation: 2 nodes/wave, clamped-batch loads for full MLP ----------------
// half = lane>>5 -> node 2p+half; gs = (lane>>4)&1 (2 edge slots); c = lane&15 (ushort4).
// Batch 1: 8 clamped loads (16 edges) issued back-to-back; overflow (deg>16) in
// clamped 4-load batches. Invalid slots read csr[0]/h[...] harmlessly, masked on accumulate.

__global__ __launch_bounds__(NT) void agg_kernel(const unsigned short* __restrict__ h,
    const int* __restrict__ row_ptr, const int* __restrict__ csr,
    unsigned short* __restrict__ aggB, int n) {
    const int t = threadIdx.x;
    const int lane = t & 63;
    const int half = lane >> 5;
    const int gs = (lane >> 4) & 1;
    const int c = lane & 15;
    const int gw = (blockIdx.x * NT + t) >> 6;
    const int nw = (gridDim.x * NT) >> 6;
    const int npairs = (n + 1) >> 1;
    for (int p = gw; p < npairs; p += nw) {
        const int node = p * 2 + half;
        const bool valid = node < n;
        const int node_c = valid ? node : (n - 1);
        const int rs = row_ptr[node_c];
        const int re = row_ptr[node_c + 1];
        float a0 = 0.f, a1 = 0.f, a2 = 0.f, a3 = 0.f;
        {
            int ce[8], si[8];
            #pragma unroll
            for (int i = 0; i < 8; ++i) {
                const int e = rs + 2 * i + gs;
                ce[i] = (e < re) ? e : 0;
            }
            #pragma unroll
            for (int i = 0; i < 8; ++i) si[i] = csr[ce[i]];
            ushort4 v[8];
            #pragma unroll
            for (int i = 0; i < 8; ++i) v[i] = *(const ushort4*)&h[(size_t)si[i] * 64 + c * 4];
            #pragma unroll
            for (int i = 0; i < 8; ++i) {
                if (rs + 2 * i + gs < re) {
                    a0 += bfbits2f(v[i].x);
                    a1 += bfbits2f(v[i].y);
                    a2 += bfbits2f(v[i].z);
                    a3 += bfbits2f(v[i].w);
                }
            }
        }
        for (int base = rs + 16; base < re; base += 8) {
            int ce[4], si[4];
            #pragma unroll
            for (int i = 0; i < 4; ++i) {
                const int e = base + 2 * i + gs;
                ce[i] = (e < re) ? e : 0;
            }
            #pragma unroll
            for (int i = 0; i < 4; ++i) si[i] = csr[ce[i]];
            ushort4 v[4];
            #pragma unroll
            for (int i = 0; i < 4; ++i) v[i] = *(const ushort4*)&h[(size_t)si[i] * 64 + c * 4];
            #pragma unroll
            for (int i = 0; i < 4; ++i) {
                if (base + 2 * i + gs < re) {
                    a0 += bfbits2f(v[i].x);
                    a1 += bfbits2f(v[i].y);
                    a2 += bfbits2f(v[i].z);
                    a3 += bfbits2f(v[i].w);
                }
            }
        }
        a0 += __shfl_xor(a0, 16, 64);
        a1 += __shfl_xor(a1, 16, 64);
        a2 += __shfl_xor(a2, 16, 64);
        a3 += __shfl_xor(a3, 16, 64);
        if (gs == 0 && valid) {
            const float inv = (re > rs) ? (1.0f / (float)(re - rs)) : 0.0f;
            ushort4 o;
            o.x = f2bfbits(a0 * inv);
            o.y = f2bfbits(a1 * inv);
            o.z = f2bfbits(a2 * inv);
            o.w = f2bfbits(a3 * inv);
            *(ushort4*)&aggB[(size_t)node * 64 + c * 4] = o;
        }
    }
}

// ---------------- MFMA GEMM: C = A1@W1 + A2@W2 + bias; norm; LAST: + (C@W2t2 + b2) ----------------
// block = 4 waves, wave = 32 rows x 64 cols (2 row-tiles x 4 col-tiles of 16x16x32 mfma).
// C/D: col = lane&15, row = (lane>>4)*4 + reg.

template<int LAST>
__global__ __launch_bounds__(NT) void gemm_mfma(
    const unsigned short* __restrict__ A1b, const unsigned short* __restrict__ W1t,
    const unsigned short* __restrict__ A2b, const unsigned short* __restrict__ W2t,
    const float* __restrict__ bias, float* __restrict__ outF,
    unsigned short* __restrict__ outB, int n,
    const unsigned short* __restrict__ W2t2, const float* __restrict__ b2) {
    const int t = threadIdx.x;
    const int lane = t & 63;
    const int w = t >> 6;
    const int r16 = lane & 15;
    const int g = lane >> 4;
    const int row0 = blockIdx.x * 128 + w * 32;

    f32x4 acc[2][4];
    #pragma unroll
    for (int i = 0; i < 2; ++i)
        #pragma unroll
        for (int j = 0; j < 4; ++j) {
            acc[i][j][0] = 0.f; acc[i][j][1] = 0.f; acc[i][j][2] = 0.f; acc[i][j][3] = 0.f;
        }

    int ra[2];
    #pragma unroll
    for (int rt = 0; rt < 2; ++rt) {
        int r = row0 + rt * 16 + r16;
        ra[rt] = (r < n) ? r : (n - 1);
    }

    #pragma unroll
    for (int kc = 0; kc < 64; kc += 32) {
        bf16x8 a1[2], a2[2];
        #pragma unroll
        for (int rt = 0; rt < 2; ++rt) {
            a1[rt] = *(const bf16x8*)&A1b[(size_t)ra[rt] * 64 + kc + g * 8];
            a2[rt] = *(const bf16x8*)&A2b[(size_t)ra[rt] * 64 + kc + g * 8];
        }
        #pragma unroll
        for (int ct = 0; ct < 4; ++ct) {
            const bf16x8 bw1 = *(const bf16x8*)&W1t[(size_t)(ct * 16 + r16) * 64 + kc + g * 8];
            const bf16x8 bw2 = *(const bf16x8*)&W2t[(size_t)(ct * 16 + r16) * 64 + kc + g * 8];
            acc[0][ct] = __builtin_amdgcn_mfma_f32_16x16x32_bf16(a1[0], bw1, acc[0][ct], 0, 0, 0);
            acc[0][ct] = __builtin_amdgcn_mfma_f32_16x16x32_bf16(a2[0], bw2, acc[0][ct], 0, 0, 0);
            acc[1][ct] = __builtin_amdgcn_mfma_f32_16x16x32_bf16(a1[1], bw1, acc[1][ct], 0, 0, 0);
            acc[1][ct] = __builtin_amdgcn_mfma_f32_16x16x32_bf16(a2[1], bw2, acc[1][ct], 0, 0, 0);
        }
    }

    float bcol[4];
    #pragma unroll
    for (int ct = 0; ct < 4; ++ct) bcol[ct] = bias[ct * 16 + r16];

    #pragma unroll
    for (int rt = 0; rt < 2; ++rt) {
        #pragma unroll
        for (int ct = 0; ct < 4; ++ct)
            #pragma unroll
            for (int reg = 0; reg < 4; ++reg) acc[rt][ct][reg] += bcol[ct];

        #pragma unroll
        for (int reg = 0; reg < 4; ++reg) {
            float ss = 0.f;
            #pragma unroll
            for (int ct = 0; ct < 4; ++ct) ss += acc[rt][ct][reg] * acc[rt][ct][reg];
            ss += __shfl_xor(ss, 1, 64);
            ss += __shfl_xor(ss, 2, 64);
            ss += __shfl_xor(ss, 4, 64);
            ss += __shfl_xor(ss, 8, 64);
            const float inv = 1.0f / fmaxf(sqrtf(ss), 1e-12f);
            #pragma unroll
            for (int ct = 0; ct < 4; ++ct)
                acc[rt][ct][reg] = fmaxf(acc[rt][ct][reg] * inv, 0.0f);
        }
    }

    if constexpr (!LAST) {
        #pragma unroll
        for (int rt = 0; rt < 2; ++rt) {
            const int rbase = row0 + rt * 16 + g * 4;
            #pragma unroll
            for (int reg = 0; reg < 4; ++reg) {
                const int rr = rbase + reg;
                if (rr < n) {
                    #pragma unroll
                    for (int ct = 0; ct < 4; ++ct)
                        outB[(size_t)rr * 64 + ct * 16 + r16] = f2bfbits(acc[rt][ct][reg]);
                }
            }
        }
    } else {
        // stage h3 tile in LDS, then out = h3 @ W2t2 + b2 (f32)
        __shared__ unsigned short h3S[128][HSTRIDE];   // 18 KB
        #pragma unroll
        for (int rt = 0; rt < 2; ++rt) {
            #pragma unroll
            for (int reg = 0; reg < 4; ++reg) {
                const int lr = w * 32 + rt * 16 + g * 4 + reg;
                #pragma unroll
                for (int ct = 0; ct < 4; ++ct)
                    h3S[lr][ct * 16 + r16] = f2bfbits(acc[rt][ct][reg]);
            }
        }
        __syncthreads();
        f32x4 acc2[2][4];
        #pragma unroll
        for (int i = 0; i < 2; ++i)
            #pragma unroll
            for (int j = 0; j < 4; ++j) { acc2[i][j][0]=0.f; acc2[i][j][1]=0.f; acc2[i][j][2]=0.f; acc2[i][j][3]=0.f; }
        #pragma unroll
        for (int kc = 0; kc < 64; kc += 32) {
            bf16x8 af[2];
            #pragma unroll
            for (int rt = 0; rt < 2; ++rt)
                af[rt] = *(const bf16x8*)&h3S[w * 32 + rt * 16 + r16][kc + g * 8];
            #pragma unroll
            for (int ct = 0; ct < 4; ++ct) {
                const bf16x8 bw = *(const bf16x8*)&W2t2[(size_t)(ct * 16 + r16) * 64 + kc + g * 8];
                acc2[0][ct] = __builtin_amdgcn_mfma_f32_16x16x32_bf16(af[0], bw, acc2[0][ct], 0, 0, 0);
                acc2[1][ct] = __builtin_amdgcn_mfma_f32_16x16x32_bf16(af[1], bw, acc2[1][ct], 0, 0, 0);
            }
        }
        float b2c[4];
        #pragma unroll
        for (int ct = 0; ct < 4; ++ct) b2c[ct] = b2[ct * 16 + r16];
        #pragma unroll
        for (int rt = 0; rt < 2; ++rt) {
            const int rbase = row0 + rt * 16 + g * 4;
            #pragma unroll
            for (int reg = 0; reg < 4; ++reg) {
                const int rr = rbase + reg;
                if (rr < n) {
                    #pragma unroll
                    for (int ct = 0; ct < 4; ++ct)
                        outF[(size_t)rr * 64 + ct * 16 + r16] = acc2[rt][ct][reg] + b2c[ct];
                }
            }
        }
    }
}

// ---------------- launch ----------------

extern "C" void kernel_launch(void* const* d_in, const int* in_sizes, int n_in,
                              void* d_out, int out_size, void* d_ws, size_t ws_size,
                              hipStream_t stream) {
    const float* x  = (const float*)d_in[0];
    const int*   ei = (const int*)  d_in[1];
    const float* W1 = (const float*)d_in[2];
    const float* b1 = (const float*)d_in[3];
    const float* Wl = (const float*)d_in[4];
    const float* bl = (const float*)d_in[5];
    const float* Wr = (const float*)d_in[6];
    const float* W2 = (const float*)d_in[7];
    const float* b2 = (const float*)d_in[8];
    float* out = (float*)d_out;

    const int n = in_sizes[0] / 128;   // 100000
    const int m = in_sizes[1] / 2;     // 1250000
    const int* src = ei;
    const int* dst = ei + m;

    const int nsb = (n + 511) >> 9;    // 196 super-buckets (<= 256)

    char* ws = (char*)d_ws;
    size_t off = 0;
    auto alloc = [&](size_t bytes) -> void* {
        void* p = ws + off;
        off = (off + bytes + 255) & ~(size_t)255;
        return p;
    };
    unsigned short* aggB    = (unsigned short*)alloc((size_t)n * 64 * 2);
    unsigned short* hbf     = (unsigned short*)alloc((size_t)n * 64 * 2);
    int*            row_ptr = (int*)alloc((size_t)(n + 1) * sizeof(int));
    unsigned*       gcur    = (unsigned*)alloc((size_t)nsb * 4);
    unsigned*       bins    = (unsigned*)alloc((size_t)nsb * SBCAP * 4);
    int*            csr     = (int*)alloc((size_t)m * 4);
    unsigned short* wt      = (unsigned short*)alloc(36864 * 2);

    const unsigned short* W1t = wt;
    const unsigned short* W2t = wt + 32768;

    const int nb1 = (m + BATCH - 1) / BATCH;   // 306
    const int gtiles = (n + 127) / 128;        // 782

    hipMemsetAsync(gcur, 0, (size_t)nsb * 4, stream);

    // A: wconv (144 blocks) || bin1 (306 blocks)
    wconv_bin1_kernel<<<WCONV_BLOCKS + nb1, NT, 0, stream>>>(W1, Wl, Wr, W2, wt,
                                                             src, dst, m, gcur, bins);
    // B: bin2 (196 blocks) || lin1 (782 blocks)
    bin2_lin1_kernel<<<nsb + gtiles, NT, 0, stream>>>(bins, gcur, row_ptr, csr, n, nsb, m,
                                                      x, W1t, b1, hbf);

    // layers 1,2: agg + GEMM(norm,relu), h in-place; layer 3: GEMM also applies W2 -> out
    for (int i = 0; i < 2; ++i) {
        agg_kernel<<<2048, NT, 0, stream>>>(hbf, row_ptr, csr, aggB, n);
        const unsigned short* Wlt = wt + 8192 + (size_t)i * 8192;
        const unsigned short* Wrt = Wlt + 4096;
        gemm_mfma<0><<<gtiles, NT, 0, stream>>>(aggB, Wlt, hbf, Wrt,
                                                bl + (size_t)i * 64,
                                                nullptr, hbf, n, nullptr, nullptr);
    }
    agg_kernel<<<2048, NT, 0, stream>>>(hbf, row_ptr, csr, aggB, n);
    gemm_mfma<1><<<gtiles, NT, 0, stream>>>(aggB, wt + 8192 + 16384,
                                            hbf, wt + 8192 + 16384 + 4096,
                                            bl + 128, out, nullptr, n, W2t, b2);
}